// Round 7
// baseline (226.012 us; speedup 1.0000x reference)
//
#include <hip/hip_runtime.h>
#include <hip/hip_bf16.h>
#include <stdint.h>

#define B_ 8
#define L_ 2048
#define V_ 8192
#define C_ 64
#define F_ 130   // 2*(C+1)

typedef float    f32x4  __attribute__((ext_vector_type(4)));
typedef float    f32x2  __attribute__((ext_vector_type(2)));
typedef short    s16x8  __attribute__((ext_vector_type(8)));
typedef __bf16   bf16x8 __attribute__((ext_vector_type(8)));
typedef uint32_t u32x4  __attribute__((ext_vector_type(4)));

#if __has_builtin(__builtin_amdgcn_exp2f)
#define EXP2(x) __builtin_amdgcn_exp2f(x)
#else
#define EXP2(x) exp2f(x)
#endif

#if __has_builtin(__builtin_elementwise_fma)
#define PK_FMA4(a,b,c) __builtin_elementwise_fma((a),(b),(c))
#else
__device__ __forceinline__ f32x4 PK_FMA4(f32x4 a, f32x4 b, f32x4 c) {
  f32x4 r; for (int i=0;i<4;++i) r[i]=fmaf(a[i],b[i],c[i]); return r;
}
#endif
#if __has_builtin(__builtin_elementwise_max)
#define PK_MAX4(a,b) __builtin_elementwise_max((a),(b))
#else
__device__ __forceinline__ f32x4 PK_MAX4(f32x4 a, f32x4 b) {
  f32x4 r; for (int i=0;i<4;++i) r[i]=fmaxf(a[i],b[i]); return r;
}
#endif

// K = 1/(2.5*ln2); w = exp(-d/2.5) = exp2(-K*d) = exp2(-sqrt(K^2*d2))
constexpr float KEXP2 = (float)(0.57707801635558535 * 0.57707801635558535);

__device__ __forceinline__ uint32_t pack2bf(float a, float b) {
  uint16_t ua = __builtin_bit_cast(uint16_t, (__bf16)a);
  uint16_t ub = __builtin_bit_cast(uint16_t, (__bf16)b);
  return (uint32_t)ua | ((uint32_t)ub << 16);
}

__device__ __forceinline__ float wave_sum(float v) {
  v += __shfl_xor(v, 1);  v += __shfl_xor(v, 2);  v += __shfl_xor(v, 4);
  v += __shfl_xor(v, 8);  v += __shfl_xor(v, 16); v += __shfl_xor(v, 32);
  return v;
}

// async global->LDS, 16B per lane: lds dest = wave-uniform base + lane*16
__device__ __forceinline__ void gload_lds16(const void* g, void* l) {
  __builtin_amdgcn_global_load_lds(
      (const __attribute__((address_space(1))) void*)g,
      (__attribute__((address_space(3))) void*)l, 16, 0, 0);
}

// ---------------------------------------------------------------------------
// PRE: blocks [0,1024): feats -> bf16 pre-swizzled 8KB k-tiles. FULL COVERAGE:
//   tile cell (ch in [0,64), kq in [0,8)) = 16B at byte ch*128 + ((kq^(ch&7))<<4).
//   Role r in [0,512): ch=r>>3, kq=(r&7)^(ch&7)  =>  dst byte = r*16 (coalesced).
//   256 threads x 2 halves cover all 512 roles  (r3-r5 BUG: only r<64 written,
//   channels 8-63 were poison -> absmax 1.0; now fixed).
//   Stage [64v][64ch] fp32 in LDS pitch 68, column XOR col' = col ^ (kq_row<<3):
//   gather bank = (68e + (ch^8kq)) mod 32 -> exact 2-way (free).
// blocks [1024,1536): verts -> vS2[p][sub64][{x',y',z',n2'}][64], 1KB tiles,
//   PRE-SCALED: x'=-2*K2*x, n2'=K2*|v|^2  => d2' = 3 fma + add.
// ---------------------------------------------------------------------------
__global__ __launch_bounds__(256) void pre_kernel(
    const float* __restrict__ verts_l, const float* __restrict__ verts_r,
    const float* __restrict__ feats_l, const float* __restrict__ feats_r,
    uint16_t* __restrict__ fT2, float* __restrict__ vS2)
{
  __shared__ float fs[64][68];
  const int blk = blockIdx.x, tid = threadIdx.x;
  if (blk < 1024) {
    const int p = blk >> 6, kt2 = blk & 63;      // 64-vert subtiles 2*kt2, 2*kt2+1
    const int side = p >> 3, bb = p & 7;
    const float* src = (side ? feats_r : feats_l) + (size_t)bb * (V_ * C_);
    #pragma unroll
    for (int sub = 0; sub < 2; ++sub) {
      const int ktile = kt2 * 2 + sub;
      const int v0 = ktile * 64;
      { // stage 64 rows x 64 ch, coalesced; column XOR-swizzle per 8-col block
        const int sv = tid >> 2, c0 = (tid & 3) * 16;
        const int m = ((sv >> 3) & 7) << 3;
        const float* s = src + (size_t)(v0 + sv) * C_ + c0;
        f32x4 a = *(const f32x4*)(s);
        f32x4 b = *(const f32x4*)(s + 4);
        f32x4 c = *(const f32x4*)(s + 8);
        f32x4 d = *(const f32x4*)(s + 12);
        *(f32x4*)&fs[sv][(c0)      ^ m] = a;
        *(f32x4*)&fs[sv][(c0 + 4)  ^ m] = b;
        *(f32x4*)&fs[sv][(c0 + 8)  ^ m] = c;
        *(f32x4*)&fs[sv][(c0 + 12) ^ m] = d;
      }
      __syncthreads();
      { // gather-swizzle, full tile: 2 roles per thread
        char* tb = (char*)fT2 + ((size_t)p * 128 + ktile) * 8192;
        #pragma unroll
        for (int half = 0; half < 2; ++half) {
          const int r  = half * 256 + tid;
          const int ch = r >> 3;
          const int kq = (r & 7) ^ (ch & 7);
          const int cs = ch ^ (kq << 3);         // swizzled staged column
          const int row0 = kq * 8;
          float f[8];
          #pragma unroll
          for (int e = 0; e < 8; ++e) f[e] = fs[row0 + e][cs];
          u32x4 val = { pack2bf(f[0], f[1]), pack2bf(f[2], f[3]),
                        pack2bf(f[4], f[5]), pack2bf(f[6], f[7]) };
          *(u32x4*)(tb + r * 16) = val;
        }
      }
      __syncthreads();
    }
  } else {
    const int blk2 = blk - 1024;
    const int p = blk2 >> 5, chunk = blk2 & 31;
    const int side = p >> 3, bb = p & 7;
    const float* src = (side ? verts_r : verts_l) + (size_t)bb * (V_ * 3);
    const int v = chunk * 256 + tid;
    const float x = src[v * 3 + 0], y = src[v * 3 + 1], z = src[v * 3 + 2];
    const float n2 = x * x + y * y + z * z;
    constexpr float M2K = -2.0f * KEXP2;
    float* d = vS2 + (size_t)p * 32768 + (size_t)(v >> 6) * 256 + (v & 63);
    d[0] = M2K * x; d[64] = M2K * y; d[128] = M2K * z; d[192] = KEXP2 * n2;
  }
}

// ---------------------------------------------------------------------------
// FUSED interp(both sides) + MLP.
// Grid 512 = 8 batches x 64 row-tiles(32 rows); bb = bid&7 pins batch -> XCD.
// Block: 512 thr = 8 waves: rowgrp g = wid&1 (16 rows) x k-quarter h = wid>>1.
// K-loop: 64 iters x 128-vert tiles, double-buffered global_load_lds.
// LDS total 53888 B -> 3 blocks/CU = 24 waves/CU (xs pitch 132: also kills the
// 4-way merge-phase bank conflict; 132r stays 16B-aligned).
// ---------------------------------------------------------------------------
__global__ __launch_bounds__(512, 6) void fused_kernel(
    const float* __restrict__ locs_l, const float* __restrict__ locs_r,
    const uint16_t* __restrict__ fT2, const float* __restrict__ vS2,
    const float* __restrict__ w1, const float* __restrict__ b1,
    const float* __restrict__ w2, const float* __restrict__ b2,
    float* __restrict__ outp)
{
  __shared__ __align__(16) char  flds[2][16384];      // 2 x (2 subtiles x 8KB)
  __shared__ __align__(16) float vlds[2][2][4][64];   // [buf][sub][comp][v]
  __shared__ __align__(16) float xs[32][132];
  __shared__ float densp[32];

  const int bid  = blockIdx.x;
  const int bb   = bid & 7;
  const int tile = bid >> 3;          // 0..63
  const int tid  = threadIdx.x;
  const int wid  = tid >> 6, lane = tid & 63;
  const int g    = wid & 1, h = wid >> 1;      // h in [0,4): 32-vert quarter
  const int ln15 = lane & 15, lg = lane >> 4;
  const int xorv = (ln15 & 7) << 4;
  const f32x4 zero4 = {0.f, 0.f, 0.f, 0.f};

  const int sub  = h >> 1;            // which 8KB subtile
  const int hh   = h & 1;             // 32-vert half within subtile
  const int abfix = sub * 8192 + ln15 * 128 + ((((hh << 2) | lg) << 4) ^ xorv);

  for (int s = 0; s < 2; ++s) {
    const int p = s * 8 + bb;
    const float* locs = (s ? locs_r : locs_l) + (size_t)bb * (L_ * 3);
    const int arow = tile * 32 + g * 16 + ln15;
    const float px = locs[arow * 3 + 0];
    const float py = locs[arow * 3 + 1];
    const float pz = locs[arow * 3 + 2];
    const float pn2p = KEXP2 * (px * px + py * py + pz * pz);
    const f32x4 px4 = {px, px, px, px};
    const f32x4 py4 = {py, py, py, py};
    const f32x4 pz4 = {pz, pz, pz, pz};
    const f32x4 pn4 = {pn2p, pn2p, pn2p, pn2p};

    const char* ftp = (const char*)fT2 + (size_t)p * (128 * 8192);
    const char* vtp = (const char*)vS2 + (size_t)p * (128 * 1024);

    f32x4 acc0 = zero4, acc1 = zero4, acc2 = zero4, acc3 = zero4;
    f32x4 densa = zero4;

    // prologue: stage 128-vert tile 0
    gload_lds16(ftp + wid * 2048 + lane * 16,        &flds[0][wid * 2048]);
    gload_lds16(ftp + wid * 2048 + 1024 + lane * 16, &flds[0][wid * 2048 + 1024]);
    if (wid < 2) gload_lds16(vtp + wid * 1024 + lane * 16, &vlds[0][wid][0][0]);
    __syncthreads();

    // strength-reduced prefetch pointers (tile kt+1)
    const char* gfn = ftp + 16384 + wid * 2048 + lane * 16;
    const char* gvn = vtp + 2048  + wid * 1024 + lane * 16;

    for (int kt = 0; kt < 64; ++kt) {
      const int cur = kt & 1;
      if (kt < 63) {   // issue next-tile loads first; land by barrier drain
        const int nxt = cur ^ 1;
        gload_lds16(gfn,        &flds[nxt][wid * 2048]);
        gload_lds16(gfn + 1024, &flds[nxt][wid * 2048 + 1024]);
        if (wid < 2) gload_lds16(gvn, &vlds[nxt][wid][0][0]);
        gfn += 16384;
        gvn += 2048;
      }
      const int kof = hh * 32 + lg * 8;
      const f32x4 vxa = *(const f32x4*)&vlds[cur][sub][0][kof];
      const f32x4 vxb = *(const f32x4*)&vlds[cur][sub][0][kof + 4];
      const f32x4 vya = *(const f32x4*)&vlds[cur][sub][1][kof];
      const f32x4 vyb = *(const f32x4*)&vlds[cur][sub][1][kof + 4];
      const f32x4 vza = *(const f32x4*)&vlds[cur][sub][2][kof];
      const f32x4 vzb = *(const f32x4*)&vlds[cur][sub][2][kof + 4];
      const f32x4 vna = *(const f32x4*)&vlds[cur][sub][3][kof];
      const f32x4 vnb = *(const f32x4*)&vlds[cur][sub][3][kof + 4];

      f32x4 d2a = PK_FMA4(vza, pz4, vna + pn4);
      d2a = PK_FMA4(vya, py4, d2a);
      d2a = PK_FMA4(vxa, px4, d2a);
      d2a = PK_MAX4(d2a, zero4);
      f32x4 d2b = PK_FMA4(vzb, pz4, vnb + pn4);
      d2b = PK_FMA4(vyb, py4, d2b);
      d2b = PK_FMA4(vxb, px4, d2b);
      d2b = PK_MAX4(d2b, zero4);

      f32x4 wa, wb;
      #pragma unroll
      for (int e = 0; e < 4; ++e) {
        wa[e] = EXP2(-__builtin_amdgcn_sqrtf(d2a[e]));
        wb[e] = EXP2(-__builtin_amdgcn_sqrtf(d2b[e]));
      }
      densa += wa;
      densa += wb;
      bf16x8 av;
      #pragma unroll
      for (int e = 0; e < 4; ++e) {
        av[e]     = (__bf16)wa[e];
        av[e + 4] = (__bf16)wb[e];
      }
      const s16x8 afrag = __builtin_bit_cast(s16x8, av);
      const char* fl = flds[cur];
      const s16x8 bf0 = *(const s16x8*)(fl + abfix);
      const s16x8 bf1 = *(const s16x8*)(fl + abfix + 2048);
      const s16x8 bf2 = *(const s16x8*)(fl + abfix + 4096);
      const s16x8 bf3 = *(const s16x8*)(fl + abfix + 6144);
      acc0 = __builtin_amdgcn_mfma_f32_16x16x32_bf16(afrag, bf0, acc0, 0, 0, 0);
      acc1 = __builtin_amdgcn_mfma_f32_16x16x32_bf16(afrag, bf1, acc1, 0, 0, 0);
      acc2 = __builtin_amdgcn_mfma_f32_16x16x32_bf16(afrag, bf2, acc2, 0, 0, 0);
      acc3 = __builtin_amdgcn_mfma_f32_16x16x32_bf16(afrag, bf3, acc3, 0, 0, 0);
      __syncthreads();
    }

    // lane -> quarter-dens of row (lane&15)
    float dens = (densa.x + densa.y) + (densa.z + densa.w);
    dens += __shfl_xor(dens, 16);
    dens += __shfl_xor(dens, 32);

    // merge 4 k-quarters through xs (phase h==0 writes, 1..3 add)
    #pragma unroll
    for (int ph = 0; ph < 4; ++ph) {
      if (h == ph) {
        if (ph == 0) {
          if (lane < 16) densp[g * 16 + lane] = dens;
          #pragma unroll
          for (int r = 0; r < 4; ++r) {
            const int row = g * 16 + lg * 4 + r;
            xs[row][s * 65 +      ln15] = acc0[r];
            xs[row][s * 65 + 16 + ln15] = acc1[r];
            xs[row][s * 65 + 32 + ln15] = acc2[r];
            xs[row][s * 65 + 48 + ln15] = acc3[r];
          }
        } else {
          if (lane < 16) densp[g * 16 + lane] += dens;
          #pragma unroll
          for (int r = 0; r < 4; ++r) {
            const int row = g * 16 + lg * 4 + r;
            xs[row][s * 65 +      ln15] += acc0[r];
            xs[row][s * 65 + 16 + ln15] += acc1[r];
            xs[row][s * 65 + 32 + ln15] += acc2[r];
            xs[row][s * 65 + 48 + ln15] += acc3[r];
          }
        }
      }
      __syncthreads();
    }
    // normalize by dens; col 64 holds raw dens
    for (int idx = tid; idx < 32 * 64; idx += 512) {
      const int row = idx >> 6, c = idx & 63;
      xs[row][s * 65 + c] *= (1.0f / densp[row]);
    }
    if (tid < 32) xs[tid][s * 65 + 64] = densp[tid];
    __syncthreads();
  }

  // -------------------- in-block MLP (fp32) --------------------
  const int r0 = wid * 4;                     // 4 rows per wave
  float hh0[4] = {0.f,0.f,0.f,0.f}, hh1[4] = {0.f,0.f,0.f,0.f};
  const float* wr0 = w1 + (size_t)lane * F_;
  const float* wr1 = w1 + (size_t)(lane + 64) * F_;

  #pragma unroll 4
  for (int i = 0; i < 128; i += 4) {
    const f32x2 a01 = *(const f32x2*)&wr0[i];
    const f32x2 a23 = *(const f32x2*)&wr0[i + 2];
    const f32x2 c01 = *(const f32x2*)&wr1[i];
    const f32x2 c23 = *(const f32x2*)&wr1[i + 2];
    #pragma unroll
    for (int r = 0; r < 4; ++r) {
      const f32x4 xv = *(const f32x4*)&xs[r0 + r][i];
      hh0[r] = fmaf(xv.x, a01.x, hh0[r]); hh0[r] = fmaf(xv.y, a01.y, hh0[r]);
      hh0[r] = fmaf(xv.z, a23.x, hh0[r]); hh0[r] = fmaf(xv.w, a23.y, hh0[r]);
      hh1[r] = fmaf(xv.x, c01.x, hh1[r]); hh1[r] = fmaf(xv.y, c01.y, hh1[r]);
      hh1[r] = fmaf(xv.z, c23.x, hh1[r]); hh1[r] = fmaf(xv.w, c23.y, hh1[r]);
    }
  }
  { // i-tail: 128,129
    const float a0 = wr0[128], a1 = wr0[129];
    const float c0 = wr1[128], c1 = wr1[129];
    #pragma unroll
    for (int r = 0; r < 4; ++r) {
      const float x0 = xs[r0 + r][128], x1 = xs[r0 + r][129];
      hh0[r] = fmaf(x0, a0, fmaf(x1, a1, hh0[r]));
      hh1[r] = fmaf(x0, c0, fmaf(x1, c1, hh1[r]));
    }
  }
  // j-tail: hidden cols 128,129 via per-row wave reduce
  const float* wr2 = w1 + 128 * F_;
  const float* wr3 = w1 + 129 * F_;
  float hp2[4], hp3[4];
  #pragma unroll
  for (int r = 0; r < 4; ++r) {
    const float xa = xs[r0 + r][lane];
    const float xb = xs[r0 + r][lane + 64];
    float p2 = wr2[lane] * xa + wr2[lane + 64] * xb;
    float p3 = wr3[lane] * xa + wr3[lane + 64] * xb;
    if (lane < 2) {
      const float xc = xs[r0 + r][128 + lane];
      p2 += wr2[128 + lane] * xc;
      p3 += wr3[128 + lane] * xc;
    }
    hp2[r] = wave_sum(p2);
    hp3[r] = wave_sum(p3);
  }
  const float b1a = b1[lane], b1b = b1[lane + 64];
  const float w2a = w2[lane], w2b = w2[lane + 64];
  const float b1c = b1[128], b1d = b1[129];
  const float w2c = w2[128], w2d = w2[129];
  const float b2v = b2[0];
  #pragma unroll
  for (int r = 0; r < 4; ++r) {
    float o = w2a * fmaxf(hh0[r] + b1a, 0.f) + w2b * fmaxf(hh1[r] + b1b, 0.f);
    o = wave_sum(o);
    if (lane == 0) {
      o += w2c * fmaxf(hp2[r] + b1c, 0.f) + w2d * fmaxf(hp3[r] + b1d, 0.f);
      outp[(size_t)bb * L_ + tile * 32 + r0 + r] = o + b2v;
    }
  }
}

// ---------------------------------------------------------------------------
extern "C" void kernel_launch(void* const* d_in, const int* in_sizes, int n_in,
                              void* d_out, int out_size, void* d_ws, size_t ws_size,
                              hipStream_t stream) {
  const float* locs_l  = (const float*)d_in[0];
  const float* locs_r  = (const float*)d_in[1];
  const float* verts_l = (const float*)d_in[2];
  const float* verts_r = (const float*)d_in[3];
  const float* feats_l = (const float*)d_in[4];
  const float* feats_r = (const float*)d_in[5];
  const float* w1 = (const float*)d_in[6];
  const float* b1 = (const float*)d_in[7];
  const float* w2 = (const float*)d_in[8];
  const float* b2 = (const float*)d_in[9];

  char* ws = (char*)d_ws;
  uint16_t* fT2 = (uint16_t*)ws;                 // 16 MiB swizzled feat tiles
  float*    vS2 = (float*)(ws + 16777216);       // 2 MiB pre-scaled vert tiles
  float*    out = (float*)d_out;

  pre_kernel<<<1536, 256, 0, stream>>>(verts_l, verts_r, feats_l, feats_r, fT2, vS2);
  fused_kernel<<<512, 512, 0, stream>>>(locs_l, locs_r, fT2, vS2,
                                        w1, b1, w2, b2, out);
}

// Round 8
// 223.734 us; speedup vs baseline: 1.0102x; 1.0102x over previous
//
#include <hip/hip_runtime.h>
#include <hip/hip_bf16.h>
#include <stdint.h>

#define B_ 8
#define L_ 2048
#define V_ 8192
#define C_ 64
#define F_ 130   // 2*(C+1)

typedef float    f32x4  __attribute__((ext_vector_type(4)));
typedef float    f32x2  __attribute__((ext_vector_type(2)));
typedef short    s16x8  __attribute__((ext_vector_type(8)));
typedef __bf16   bf16x8 __attribute__((ext_vector_type(8)));
typedef uint32_t u32x4  __attribute__((ext_vector_type(4)));

#if __has_builtin(__builtin_amdgcn_exp2f)
#define EXP2(x) __builtin_amdgcn_exp2f(x)
#else
#define EXP2(x) exp2f(x)
#endif

#if __has_builtin(__builtin_elementwise_fma)
#define PK_FMA4(a,b,c) __builtin_elementwise_fma((a),(b),(c))
#else
__device__ __forceinline__ f32x4 PK_FMA4(f32x4 a, f32x4 b, f32x4 c) {
  f32x4 r; for (int i=0;i<4;++i) r[i]=fmaf(a[i],b[i],c[i]); return r;
}
#endif
#if __has_builtin(__builtin_elementwise_max)
#define PK_MAX4(a,b) __builtin_elementwise_max((a),(b))
#else
__device__ __forceinline__ f32x4 PK_MAX4(f32x4 a, f32x4 b) {
  f32x4 r; for (int i=0;i<4;++i) r[i]=fmaxf(a[i],b[i]); return r;
}
#endif

// K = 1/(2.5*ln2); w = exp(-d/2.5) = exp2(-K*d) = exp2(-sqrt(K^2*d2))
constexpr float KEXP2 = (float)(0.57707801635558535 * 0.57707801635558535);

__device__ __forceinline__ uint32_t pack2bf(float a, float b) {
  uint16_t ua = __builtin_bit_cast(uint16_t, (__bf16)a);
  uint16_t ub = __builtin_bit_cast(uint16_t, (__bf16)b);
  return (uint32_t)ua | ((uint32_t)ub << 16);
}

__device__ __forceinline__ float wave_sum(float v) {
  v += __shfl_xor(v, 1);  v += __shfl_xor(v, 2);  v += __shfl_xor(v, 4);
  v += __shfl_xor(v, 8);  v += __shfl_xor(v, 16); v += __shfl_xor(v, 32);
  return v;
}

// async global->LDS, 16B per lane: lds dest = wave-uniform base + lane*16
__device__ __forceinline__ void gload_lds16(const void* g, void* l) {
  __builtin_amdgcn_global_load_lds(
      (const __attribute__((address_space(1))) void*)g,
      (__attribute__((address_space(3))) void*)l, 16, 0, 0);
}

// ---------------------------------------------------------------------------
// PRE: unchanged from round 7 (passing + full coverage).
// blocks [0,1024): feats -> bf16 pre-swizzled 8KB k-tiles.
// blocks [1024,1536): verts -> vS2 pre-scaled {x',y',z',n2'} 1KB tiles.
// ---------------------------------------------------------------------------
__global__ __launch_bounds__(256) void pre_kernel(
    const float* __restrict__ verts_l, const float* __restrict__ verts_r,
    const float* __restrict__ feats_l, const float* __restrict__ feats_r,
    uint16_t* __restrict__ fT2, float* __restrict__ vS2)
{
  __shared__ float fs[64][68];
  const int blk = blockIdx.x, tid = threadIdx.x;
  if (blk < 1024) {
    const int p = blk >> 6, kt2 = blk & 63;      // 64-vert subtiles 2*kt2, 2*kt2+1
    const int side = p >> 3, bb = p & 7;
    const float* src = (side ? feats_r : feats_l) + (size_t)bb * (V_ * C_);
    #pragma unroll
    for (int sub = 0; sub < 2; ++sub) {
      const int ktile = kt2 * 2 + sub;
      const int v0 = ktile * 64;
      { // stage 64 rows x 64 ch, coalesced; column XOR-swizzle per 8-col block
        const int sv = tid >> 2, c0 = (tid & 3) * 16;
        const int m = ((sv >> 3) & 7) << 3;
        const float* s = src + (size_t)(v0 + sv) * C_ + c0;
        f32x4 a = *(const f32x4*)(s);
        f32x4 b = *(const f32x4*)(s + 4);
        f32x4 c = *(const f32x4*)(s + 8);
        f32x4 d = *(const f32x4*)(s + 12);
        *(f32x4*)&fs[sv][(c0)      ^ m] = a;
        *(f32x4*)&fs[sv][(c0 + 4)  ^ m] = b;
        *(f32x4*)&fs[sv][(c0 + 8)  ^ m] = c;
        *(f32x4*)&fs[sv][(c0 + 12) ^ m] = d;
      }
      __syncthreads();
      { // gather-swizzle, full tile: 2 roles per thread (512 roles total)
        char* tb = (char*)fT2 + ((size_t)p * 128 + ktile) * 8192;
        #pragma unroll
        for (int half = 0; half < 2; ++half) {
          const int r  = half * 256 + tid;
          const int ch = r >> 3;
          const int kq = (r & 7) ^ (ch & 7);
          const int cs = ch ^ (kq << 3);         // swizzled staged column
          const int row0 = kq * 8;
          float f[8];
          #pragma unroll
          for (int e = 0; e < 8; ++e) f[e] = fs[row0 + e][cs];
          u32x4 val = { pack2bf(f[0], f[1]), pack2bf(f[2], f[3]),
                        pack2bf(f[4], f[5]), pack2bf(f[6], f[7]) };
          *(u32x4*)(tb + r * 16) = val;
        }
      }
      __syncthreads();
    }
  } else {
    const int blk2 = blk - 1024;
    const int p = blk2 >> 5, chunk = blk2 & 31;
    const int side = p >> 3, bb = p & 7;
    const float* src = (side ? verts_r : verts_l) + (size_t)bb * (V_ * 3);
    const int v = chunk * 256 + tid;
    const float x = src[v * 3 + 0], y = src[v * 3 + 1], z = src[v * 3 + 2];
    const float n2 = x * x + y * y + z * z;
    constexpr float M2K = -2.0f * KEXP2;
    float* d = vS2 + (size_t)p * 32768 + (size_t)(v >> 6) * 256 + (v & 63);
    d[0] = M2K * x; d[64] = M2K * y; d[128] = M2K * z; d[192] = KEXP2 * n2;
  }
}

// ---------------------------------------------------------------------------
// FUSED interp(both sides) + MLP.
// Round-8 change: K-loop uses 3-buffer rotation + COUNTED vmcnt + raw barrier
// (T4): per iter {issue tile kt+1 -> buf[(kt+1)%3]; s_waitcnt vmcnt(n_own);
// s_barrier; compute buf[kt%3]}. The counted wait only requires tile kt
// (issued LAST iter) landed; this iter's loads stay in flight across the
// barrier -- removes the per-iter vmcnt(0) drain __syncthreads forced.
// WAR safe: issued buffer last read 3 iters (>=2 barriers) ago, reads
// consumed by MFMA lgkmcnt before that barrier. vmcnt(0) only at kt=63.
// ---------------------------------------------------------------------------
__global__ __launch_bounds__(512, 4) void fused_kernel(
    const float* __restrict__ locs_l, const float* __restrict__ locs_r,
    const uint16_t* __restrict__ fT2, const float* __restrict__ vS2,
    const float* __restrict__ w1, const float* __restrict__ b1,
    const float* __restrict__ w2, const float* __restrict__ b2,
    float* __restrict__ outp)
{
  __shared__ __align__(16) char  flds[3][16384];      // 3 x (2 subtiles x 8KB)
  __shared__ __align__(16) float vlds[3][2][4][64];   // [buf][sub][comp][v]
  __shared__ __align__(16) float xs[32][132];
  __shared__ float densp[32];

  const int bid  = blockIdx.x;
  const int bb   = bid & 7;
  const int tile = bid >> 3;          // 0..63
  const int tid  = threadIdx.x;
  const int wid  = tid >> 6, lane = tid & 63;
  const int g    = wid & 1, h = wid >> 1;      // h in [0,4): 32-vert quarter
  const int ln15 = lane & 15, lg = lane >> 4;
  const int xorv = (ln15 & 7) << 4;
  const f32x4 zero4 = {0.f, 0.f, 0.f, 0.f};

  const int sub  = h >> 1;            // which 8KB subtile
  const int hh   = h & 1;             // 32-vert half within subtile
  const int abfix = sub * 8192 + ln15 * 128 + ((((hh << 2) | lg) << 4) ^ xorv);

  for (int s = 0; s < 2; ++s) {
    const int p = s * 8 + bb;
    const float* locs = (s ? locs_r : locs_l) + (size_t)bb * (L_ * 3);
    const int arow = tile * 32 + g * 16 + ln15;
    const float px = locs[arow * 3 + 0];
    const float py = locs[arow * 3 + 1];
    const float pz = locs[arow * 3 + 2];
    const float pn2p = KEXP2 * (px * px + py * py + pz * pz);
    const f32x4 px4 = {px, px, px, px};
    const f32x4 py4 = {py, py, py, py};
    const f32x4 pz4 = {pz, pz, pz, pz};
    const f32x4 pn4 = {pn2p, pn2p, pn2p, pn2p};

    const char* ftp = (const char*)fT2 + (size_t)p * (128 * 8192);
    const char* vtp = (const char*)vS2 + (size_t)p * (128 * 1024);

    f32x4 acc0 = zero4, acc1 = zero4, acc2 = zero4, acc3 = zero4;
    f32x4 densa = zero4;

    // prologue: stage 128-vert tile 0 into buf 0
    gload_lds16(ftp + wid * 2048 + lane * 16,        &flds[0][wid * 2048]);
    gload_lds16(ftp + wid * 2048 + 1024 + lane * 16, &flds[0][wid * 2048 + 1024]);
    if (wid < 2) gload_lds16(vtp + wid * 1024 + lane * 16, &vlds[0][wid][0][0]);

    // strength-reduced prefetch pointers (tile kt+1)
    const char* gfn = ftp + 16384 + wid * 2048 + lane * 16;
    const char* gvn = vtp + 2048  + wid * 1024 + lane * 16;

    int cur = 0, nxt = 1;
    for (int kt = 0; kt < 64; ++kt) {
      if (kt < 63) {   // issue next tile; counted wait keeps it in flight
        gload_lds16(gfn,        &flds[nxt][wid * 2048]);
        gload_lds16(gfn + 1024, &flds[nxt][wid * 2048 + 1024]);
        if (wid < 2) {
          gload_lds16(gvn, &vlds[nxt][wid][0][0]);
          asm volatile("s_waitcnt vmcnt(3)" ::: "memory");
        } else {
          asm volatile("s_waitcnt vmcnt(2)" ::: "memory");
        }
        gfn += 16384;
        gvn += 2048;
      } else {
        asm volatile("s_waitcnt vmcnt(0)" ::: "memory");
      }
      __builtin_amdgcn_s_barrier();   // all waves' tile-kt loads landed

      const int kof = hh * 32 + lg * 8;
      const f32x4 vxa = *(const f32x4*)&vlds[cur][sub][0][kof];
      const f32x4 vxb = *(const f32x4*)&vlds[cur][sub][0][kof + 4];
      const f32x4 vya = *(const f32x4*)&vlds[cur][sub][1][kof];
      const f32x4 vyb = *(const f32x4*)&vlds[cur][sub][1][kof + 4];
      const f32x4 vza = *(const f32x4*)&vlds[cur][sub][2][kof];
      const f32x4 vzb = *(const f32x4*)&vlds[cur][sub][2][kof + 4];
      const f32x4 vna = *(const f32x4*)&vlds[cur][sub][3][kof];
      const f32x4 vnb = *(const f32x4*)&vlds[cur][sub][3][kof + 4];

      f32x4 d2a = PK_FMA4(vza, pz4, vna + pn4);
      d2a = PK_FMA4(vya, py4, d2a);
      d2a = PK_FMA4(vxa, px4, d2a);
      d2a = PK_MAX4(d2a, zero4);
      f32x4 d2b = PK_FMA4(vzb, pz4, vnb + pn4);
      d2b = PK_FMA4(vyb, py4, d2b);
      d2b = PK_FMA4(vxb, px4, d2b);
      d2b = PK_MAX4(d2b, zero4);

      f32x4 wa, wb;
      #pragma unroll
      for (int e = 0; e < 4; ++e) {
        wa[e] = EXP2(-__builtin_amdgcn_sqrtf(d2a[e]));
        wb[e] = EXP2(-__builtin_amdgcn_sqrtf(d2b[e]));
      }
      densa += wa;
      densa += wb;
      bf16x8 av;
      #pragma unroll
      for (int e = 0; e < 4; ++e) {
        av[e]     = (__bf16)wa[e];
        av[e + 4] = (__bf16)wb[e];
      }
      const s16x8 afrag = __builtin_bit_cast(s16x8, av);
      const char* fl = flds[cur];
      const s16x8 bf0 = *(const s16x8*)(fl + abfix);
      const s16x8 bf1 = *(const s16x8*)(fl + abfix + 2048);
      const s16x8 bf2 = *(const s16x8*)(fl + abfix + 4096);
      const s16x8 bf3 = *(const s16x8*)(fl + abfix + 6144);
      acc0 = __builtin_amdgcn_mfma_f32_16x16x32_bf16(afrag, bf0, acc0, 0, 0, 0);
      acc1 = __builtin_amdgcn_mfma_f32_16x16x32_bf16(afrag, bf1, acc1, 0, 0, 0);
      acc2 = __builtin_amdgcn_mfma_f32_16x16x32_bf16(afrag, bf2, acc2, 0, 0, 0);
      acc3 = __builtin_amdgcn_mfma_f32_16x16x32_bf16(afrag, bf3, acc3, 0, 0, 0);

      cur = (cur == 2) ? 0 : cur + 1;
      nxt = (nxt == 2) ? 0 : nxt + 1;
    }

    // lane -> quarter-dens of row (lane&15)
    float dens = (densa.x + densa.y) + (densa.z + densa.w);
    dens += __shfl_xor(dens, 16);
    dens += __shfl_xor(dens, 32);

    // merge 4 k-quarters through xs (phase h==0 writes, 1..3 add)
    #pragma unroll
    for (int ph = 0; ph < 4; ++ph) {
      if (h == ph) {
        if (ph == 0) {
          if (lane < 16) densp[g * 16 + lane] = dens;
          #pragma unroll
          for (int r = 0; r < 4; ++r) {
            const int row = g * 16 + lg * 4 + r;
            xs[row][s * 65 +      ln15] = acc0[r];
            xs[row][s * 65 + 16 + ln15] = acc1[r];
            xs[row][s * 65 + 32 + ln15] = acc2[r];
            xs[row][s * 65 + 48 + ln15] = acc3[r];
          }
        } else {
          if (lane < 16) densp[g * 16 + lane] += dens;
          #pragma unroll
          for (int r = 0; r < 4; ++r) {
            const int row = g * 16 + lg * 4 + r;
            xs[row][s * 65 +      ln15] += acc0[r];
            xs[row][s * 65 + 16 + ln15] += acc1[r];
            xs[row][s * 65 + 32 + ln15] += acc2[r];
            xs[row][s * 65 + 48 + ln15] += acc3[r];
          }
        }
      }
      __syncthreads();
    }
    // normalize by dens; col 64 holds raw dens
    for (int idx = tid; idx < 32 * 64; idx += 512) {
      const int row = idx >> 6, c = idx & 63;
      xs[row][s * 65 + c] *= (1.0f / densp[row]);
    }
    if (tid < 32) xs[tid][s * 65 + 64] = densp[tid];
    __syncthreads();
  }

  // -------------------- in-block MLP (fp32) --------------------
  const int r0 = wid * 4;                     // 4 rows per wave
  float hh0[4] = {0.f,0.f,0.f,0.f}, hh1[4] = {0.f,0.f,0.f,0.f};
  const float* wr0 = w1 + (size_t)lane * F_;
  const float* wr1 = w1 + (size_t)(lane + 64) * F_;

  #pragma unroll 4
  for (int i = 0; i < 128; i += 4) {
    const f32x2 a01 = *(const f32x2*)&wr0[i];
    const f32x2 a23 = *(const f32x2*)&wr0[i + 2];
    const f32x2 c01 = *(const f32x2*)&wr1[i];
    const f32x2 c23 = *(const f32x2*)&wr1[i + 2];
    #pragma unroll
    for (int r = 0; r < 4; ++r) {
      const f32x4 xv = *(const f32x4*)&xs[r0 + r][i];
      hh0[r] = fmaf(xv.x, a01.x, hh0[r]); hh0[r] = fmaf(xv.y, a01.y, hh0[r]);
      hh0[r] = fmaf(xv.z, a23.x, hh0[r]); hh0[r] = fmaf(xv.w, a23.y, hh0[r]);
      hh1[r] = fmaf(xv.x, c01.x, hh1[r]); hh1[r] = fmaf(xv.y, c01.y, hh1[r]);
      hh1[r] = fmaf(xv.z, c23.x, hh1[r]); hh1[r] = fmaf(xv.w, c23.y, hh1[r]);
    }
  }
  { // i-tail: 128,129
    const float a0 = wr0[128], a1 = wr0[129];
    const float c0 = wr1[128], c1 = wr1[129];
    #pragma unroll
    for (int r = 0; r < 4; ++r) {
      const float x0 = xs[r0 + r][128], x1 = xs[r0 + r][129];
      hh0[r] = fmaf(x0, a0, fmaf(x1, a1, hh0[r]));
      hh1[r] = fmaf(x0, c0, fmaf(x1, c1, hh1[r]));
    }
  }
  // j-tail: hidden cols 128,129 via per-row wave reduce
  const float* wr2 = w1 + 128 * F_;
  const float* wr3 = w1 + 129 * F_;
  float hp2[4], hp3[4];
  #pragma unroll
  for (int r = 0; r < 4; ++r) {
    const float xa = xs[r0 + r][lane];
    const float xb = xs[r0 + r][lane + 64];
    float p2 = wr2[lane] * xa + wr2[lane + 64] * xb;
    float p3 = wr3[lane] * xa + wr3[lane + 64] * xb;
    if (lane < 2) {
      const float xc = xs[r0 + r][128 + lane];
      p2 += wr2[128 + lane] * xc;
      p3 += wr3[128 + lane] * xc;
    }
    hp2[r] = wave_sum(p2);
    hp3[r] = wave_sum(p3);
  }
  const float b1a = b1[lane], b1b = b1[lane + 64];
  const float w2a = w2[lane], w2b = w2[lane + 64];
  const float b1c = b1[128], b1d = b1[129];
  const float w2c = w2[128], w2d = w2[129];
  const float b2v = b2[0];
  #pragma unroll
  for (int r = 0; r < 4; ++r) {
    float o = w2a * fmaxf(hh0[r] + b1a, 0.f) + w2b * fmaxf(hh1[r] + b1b, 0.f);
    o = wave_sum(o);
    if (lane == 0) {
      o += w2c * fmaxf(hp2[r] + b1c, 0.f) + w2d * fmaxf(hp3[r] + b1d, 0.f);
      outp[(size_t)bb * L_ + tile * 32 + r0 + r] = o + b2v;
    }
  }
}

// ---------------------------------------------------------------------------
extern "C" void kernel_launch(void* const* d_in, const int* in_sizes, int n_in,
                              void* d_out, int out_size, void* d_ws, size_t ws_size,
                              hipStream_t stream) {
  const float* locs_l  = (const float*)d_in[0];
  const float* locs_r  = (const float*)d_in[1];
  const float* verts_l = (const float*)d_in[2];
  const float* verts_r = (const float*)d_in[3];
  const float* feats_l = (const float*)d_in[4];
  const float* feats_r = (const float*)d_in[5];
  const float* w1 = (const float*)d_in[6];
  const float* b1 = (const float*)d_in[7];
  const float* w2 = (const float*)d_in[8];
  const float* b2 = (const float*)d_in[9];

  char* ws = (char*)d_ws;
  uint16_t* fT2 = (uint16_t*)ws;                 // 16 MiB swizzled feat tiles
  float*    vS2 = (float*)(ws + 16777216);       // 2 MiB pre-scaled vert tiles
  float*    out = (float*)d_out;

  pre_kernel<<<1536, 256, 0, stream>>>(verts_l, verts_r, feats_l, feats_r, fT2, vS2);
  fused_kernel<<<512, 512, 0, stream>>>(locs_l, locs_r, fT2, vS2,
                                        w1, b1, w2, b2, out);
}